// Round 1
// baseline (1650.385 us; speedup 1.0000x reference)
//
#include <hip/hip_runtime.h>

#define N_NODES 10000
#define N_EDGES 160000
#define N_REL 4
#define IN_DIM 15
#define HID 512
#define N_GRAPHS 64

// ---------------- workspace layout (float offsets) ----------------
#define OFF_CNT   0                      // [N_NODES*N_REL]          = 40000   (becomes inv-count)
#define OFF_SUM1  40000                  // [N_NODES*N_REL*IN_DIM]   = 600000
#define OFF_SUM2  640000                 // [N_NODES*N_REL*HID]      = 20480000  (contiguous [n][r*HID+d] = [n][2048])
#define OFF_GCNT  21120000               // [N_GRAPHS]               = 64
#define ZERO_FLOATS 21120064             // cnt+sum1+sum2+gcnt zeroed in one memset
#define OFF_H     21120064               // [N_NODES*HID]            = 5120000
#define OFF_H2    26240064               // [N_NODES*HID]            = 5120000
// total = 31360064 floats = 125.44 MB

// ---------------- kernels ----------------

// L1 edge aggregation: 16 threads/edge (15 dims + 1 count)
__global__ void edge_agg1(const float* __restrict__ x, const int* __restrict__ src,
                          const int* __restrict__ tgt, const int* __restrict__ et,
                          float* __restrict__ cnts, float* __restrict__ sums1) {
    int tid = blockIdx.x * blockDim.x + threadIdx.x;
    if (tid >= N_EDGES * 16) return;
    int e = tid >> 4, k = tid & 15;
    int seg = tgt[e] * N_REL + et[e];
    if (k == 15) { atomicAdd(&cnts[seg], 1.0f); return; }
    atomicAdd(&sums1[seg * IN_DIM + k], x[src[e] * IN_DIM + k]);
}

// counts -> 1/max(cnt,1) in place
__global__ void invc_kernel(float* __restrict__ c) {
    int i = blockIdx.x * blockDim.x + threadIdx.x;
    if (i < N_NODES * N_REL) c[i] = 1.0f / fmaxf(c[i], 1.0f);
}

// layer 1: h[n,o] = relu(b1[o] + sum_k f[k]*Wcat[k,o]); f = [mean_r(15)*4 | x(15)] (75 dims)
__global__ __launch_bounds__(HID) void layer1(
        const float* __restrict__ x, const float* __restrict__ sums1,
        const float* __restrict__ invc, const float* __restrict__ W_rel,
        const float* __restrict__ W_root, const float* __restrict__ b,
        float* __restrict__ h) {
    int n = blockIdx.x;
    __shared__ float f[N_REL * IN_DIM + IN_DIM];   // 75
    int t = threadIdx.x;
    if (t < N_REL * IN_DIM) {
        f[t] = sums1[n * N_REL * IN_DIM + t] * invc[n * N_REL + t / IN_DIM];
    } else if (t < N_REL * IN_DIM + IN_DIM) {
        f[t] = x[n * IN_DIM + (t - N_REL * IN_DIM)];
    }
    __syncthreads();
    int o = t;
    float acc = b[o];
    #pragma unroll
    for (int k = 0; k < N_REL * IN_DIM; ++k) acc = fmaf(f[k], W_rel[k * HID + o], acc);
    #pragma unroll
    for (int k = 0; k < IN_DIM; ++k) acc = fmaf(f[60 + k], W_root[k * HID + o], acc);
    h[(long)n * HID + o] = fmaxf(acc, 0.0f);
}

// L2 edge aggregation: float4 gather of h[src], 4 scalar atomics into sums2[seg]
__global__ void edge_agg2(const float* __restrict__ h, const int* __restrict__ src,
                          const int* __restrict__ tgt, const int* __restrict__ et,
                          float* __restrict__ sums2) {
    long tid = (long)blockIdx.x * blockDim.x + threadIdx.x;
    if (tid >= (long)N_EDGES * (HID / 4)) return;
    int e  = (int)(tid >> 7);          // HID/4 = 128 float4 per edge
    int d4 = ((int)tid & 127) << 2;
    int seg = tgt[e] * N_REL + et[e];
    const float4 v = *(const float4*)(h + (long)src[e] * HID + d4);
    float* dst = sums2 + (long)seg * HID + d4;
    atomicAdd(dst + 0, v.x);
    atomicAdd(dst + 1, v.y);
    atomicAdd(dst + 2, v.z);
    atomicAdd(dst + 3, v.w);
}

// layer 2 GEMM: h2[n,o] = relu(b2[o] + sum_{k<2560} A[n,k] * B[k,o])
//   A[n,k] = k<2048 ? sums2[n*2048+k] * invc[n*4 + k/512] : h[n*512 + k-2048]
//   B[k,o] = k<2048 ? W2_rel[k*512+o] : W2_root[(k-2048)*512+o]
#define BM 64
#define BN 64
#define BK 16
#define KTOT (N_REL * HID + HID)   // 2560
__global__ __launch_bounds__(256) void layer2_gemm(
        const float* __restrict__ sums2, const float* __restrict__ invc,
        const float* __restrict__ h, const float* __restrict__ W_rel,
        const float* __restrict__ W_root, const float* __restrict__ b,
        float* __restrict__ h2) {
    const int bx = blockIdx.x;        // N tile: 0..7
    const int by = blockIdx.y;        // M tile: 0..156
    const int tid = threadIdx.x;
    const int tx = tid & 15, ty = tid >> 4;

    __shared__ float As[BK][BM];      // transposed store, broadcast reads
    __shared__ float Bs[BK][BN];      // row = 256B, float4-aligned

    float acc[4][4] = {};
    const int row0  = by * BM;
    const int col0g = bx * BN;

    const int am  = tid >> 2;           // 0..63
    const int ak0 = (tid & 3) * 4;      // 0,4,8,12
    const int bk  = tid >> 4;           // 0..15
    const int bc0 = (tid & 15) * 4;     // 0..60

    for (int k0 = 0; k0 < KTOT; k0 += BK) {
        // ---- load A tile (virtual, with per-rel mean scaling) ----
        int n = row0 + am;
        float4 av = make_float4(0.f, 0.f, 0.f, 0.f);
        int kg = k0 + ak0;
        if (n < N_NODES) {
            if (kg < N_REL * HID) {
                av = *(const float4*)(sums2 + (long)n * (N_REL * HID) + kg);
                float s = invc[n * N_REL + (kg >> 9)];
                av.x *= s; av.y *= s; av.z *= s; av.w *= s;
            } else {
                av = *(const float4*)(h + (long)n * HID + (kg - N_REL * HID));
            }
        }
        As[ak0 + 0][am] = av.x;
        As[ak0 + 1][am] = av.y;
        As[ak0 + 2][am] = av.z;
        As[ak0 + 3][am] = av.w;
        // ---- load B tile ----
        {
            int kgb = k0 + bk;
            const float* Brow = (kgb < N_REL * HID) ? (W_rel + (long)kgb * HID)
                                                    : (W_root + (long)(kgb - N_REL * HID) * HID);
            *(float4*)&Bs[bk][bc0] = *(const float4*)(Brow + col0g + bc0);
        }
        __syncthreads();
        #pragma unroll
        for (int kk = 0; kk < BK; ++kk) {
            float a[4], bb[4];
            #pragma unroll
            for (int i = 0; i < 4; ++i) a[i] = As[kk][ty * 4 + i];
            #pragma unroll
            for (int j = 0; j < 4; ++j) bb[j] = Bs[kk][tx * 4 + j];
            #pragma unroll
            for (int i = 0; i < 4; ++i)
                #pragma unroll
                for (int j = 0; j < 4; ++j)
                    acc[i][j] = fmaf(a[i], bb[j], acc[i][j]);
        }
        __syncthreads();
    }
    // ---- epilogue: +bias, relu ----
    #pragma unroll
    for (int i = 0; i < 4; ++i) {
        int n = row0 + ty * 4 + i;
        if (n >= N_NODES) break;
        #pragma unroll
        for (int j = 0; j < 4; ++j) {
            int c = col0g + tx * 4 + j;
            h2[(long)n * HID + c] = fmaxf(acc[i][j] + b[c], 0.0f);
        }
    }
}

// pooling: accumulate per-graph sums + counts
__global__ void pool_acc(const float* __restrict__ h2, const int* __restrict__ batch,
                         float* __restrict__ out, float* __restrict__ gcnt) {
    long tid = (long)blockIdx.x * blockDim.x + threadIdx.x;
    if (tid >= (long)N_NODES * HID) return;
    int n = (int)(tid >> 9), d = (int)tid & (HID - 1);
    int g = batch[n];
    atomicAdd(&out[g * HID + d], h2[tid]);
    if (d == 0) atomicAdd(&gcnt[g], 1.0f);
}

__global__ void pool_div(float* __restrict__ out, const float* __restrict__ gcnt) {
    int tid = blockIdx.x * blockDim.x + threadIdx.x;
    if (tid >= N_GRAPHS * HID) return;
    out[tid] /= fmaxf(gcnt[tid >> 9], 1.0f);
}

// ---------------- launch ----------------
extern "C" void kernel_launch(void* const* d_in, const int* in_sizes, int n_in,
                              void* d_out, int out_size, void* d_ws, size_t ws_size,
                              hipStream_t stream) {
    const float* x       = (const float*)d_in[0];
    const int*   ei      = (const int*)d_in[1];          // [2, E]
    const int*   src     = ei;
    const int*   tgt     = ei + N_EDGES;
    const int*   etype   = (const int*)d_in[2];
    const int*   batch   = (const int*)d_in[3];
    const float* W1_rel  = (const float*)d_in[4];
    const float* W1_root = (const float*)d_in[5];
    const float* b1      = (const float*)d_in[6];
    const float* W2_rel  = (const float*)d_in[7];
    const float* W2_root = (const float*)d_in[8];
    const float* b2      = (const float*)d_in[9];
    float* out = (float*)d_out;

    float* ws    = (float*)d_ws;
    float* cnts  = ws + OFF_CNT;     // becomes inv-count after invc_kernel
    float* sums1 = ws + OFF_SUM1;
    float* sums2 = ws + OFF_SUM2;
    float* gcnt  = ws + OFF_GCNT;
    float* h     = ws + OFF_H;
    float* h2    = ws + OFF_H2;

    // zero accumulators (cnt|sum1|sum2|gcnt contiguous) and output
    hipMemsetAsync(ws, 0, (size_t)ZERO_FLOATS * sizeof(float), stream);
    hipMemsetAsync(d_out, 0, (size_t)N_GRAPHS * HID * sizeof(float), stream);

    // layer 1 aggregation
    {
        int total = N_EDGES * 16;
        edge_agg1<<<(total + 255) / 256, 256, 0, stream>>>(x, src, tgt, etype, cnts, sums1);
    }
    invc_kernel<<<(N_NODES * N_REL + 255) / 256, 256, 0, stream>>>(cnts);
    layer1<<<N_NODES, HID, 0, stream>>>(x, sums1, cnts, W1_rel, W1_root, b1, h);

    // layer 2 aggregation
    {
        long total = (long)N_EDGES * (HID / 4);
        edge_agg2<<<(int)((total + 255) / 256), 256, 0, stream>>>(h, src, tgt, etype, sums2);
    }
    // layer 2 GEMM
    {
        dim3 grid(HID / BN, (N_NODES + BM - 1) / BM);
        layer2_gemm<<<grid, 256, 0, stream>>>(sums2, cnts, h, W2_rel, W2_root, b2, h2);
    }

    // global mean pool
    {
        long total = (long)N_NODES * HID;
        pool_acc<<<(int)((total + 255) / 256), 256, 0, stream>>>(h2, batch, out, gcnt);
        pool_div<<<(N_GRAPHS * HID + 255) / 256, 256, 0, stream>>>(out, gcnt);
    }
}

// Round 2
// 785.146 us; speedup vs baseline: 2.1020x; 2.1020x over previous
//
#include <hip/hip_runtime.h>

#define N_NODES 10000
#define N_EDGES 160000
#define N_REL 4
#define IN_DIM 15
#define HID 512
#define N_GRAPHS 64
#define NSEG (N_NODES * N_REL)          // 40000

// ---------------- workspace layout ----------------
// ints (element offsets into (int*)d_ws):
#define IOFF_HIST   0                   // [40000]
#define IOFF_ROWPTR 40000               // [40001]
#define IOFF_CURSOR 80001               // [40000]
#define IOFF_ELIST  120001              // [160000]  (stores src node id per binned edge)
// floats (element offsets into (float*)d_ws), 16B-aligned where vectorized:
#define FOFF_MEAN1  280004              // [NSEG*IN_DIM]   = 600000
#define FOFF_H      880004              // [N_NODES*HID]   = 5120000   (16B aligned)
#define FOFF_MEAN2  6000004             // [NSEG*HID]      = 20480000  (16B aligned)
#define FOFF_GCNT   26480004            // [N_GRAPHS]
// total = 26,480,068 floats ≈ 105.9 MB

// ---------------- CSR build ----------------
__global__ void hist_kernel(const int* __restrict__ tgt, const int* __restrict__ et,
                            int* __restrict__ hist) {
    int e = blockIdx.x * blockDim.x + threadIdx.x;
    if (e >= N_EDGES) return;
    atomicAdd(&hist[tgt[e] * N_REL + et[e]], 1);
}

__global__ __launch_bounds__(1024) void scan_kernel(const int* __restrict__ hist,
                                                    int* __restrict__ rowptr,
                                                    int* __restrict__ cursor) {
    __shared__ int psums[1024];
    const int t = threadIdx.x;
    const int CH = (NSEG + 1023) / 1024;      // 40
    const int base = t * CH;
    int s = 0;
    for (int i = 0; i < CH; ++i) {
        int idx = base + i;
        if (idx < NSEG) s += hist[idx];
    }
    psums[t] = s;
    __syncthreads();
    for (int off = 1; off < 1024; off <<= 1) {
        int v = 0;
        if (t >= off) v = psums[t - off];
        __syncthreads();
        if (t >= off) psums[t] += v;
        __syncthreads();
    }
    int run = (t == 0) ? 0 : psums[t - 1];    // exclusive prefix of this chunk
    for (int i = 0; i < CH; ++i) {
        int idx = base + i;
        if (idx < NSEG) {
            rowptr[idx] = run;
            cursor[idx] = run;
            run += hist[idx];
        }
    }
    if (t == 1023) rowptr[NSEG] = psums[1023];
}

__global__ void bin_kernel(const int* __restrict__ src, const int* __restrict__ tgt,
                           const int* __restrict__ et, int* __restrict__ cursor,
                           int* __restrict__ elist) {
    int e = blockIdx.x * blockDim.x + threadIdx.x;
    if (e >= N_EDGES) return;
    int seg = tgt[e] * N_REL + et[e];
    int pos = atomicAdd(&cursor[seg], 1);
    elist[pos] = src[e];
}

// ---------------- layer 1 ----------------
// mean1[seg][k] = mean over edges in seg of x[src][k];  16 lanes per segment (15 used)
__global__ void mean1_kernel(const float* __restrict__ x, const int* __restrict__ rowptr,
                             const int* __restrict__ elist, float* __restrict__ mean1) {
    int tid = blockIdx.x * blockDim.x + threadIdx.x;
    if (tid >= NSEG * 16) return;
    int seg = tid >> 4, k = tid & 15;
    if (k >= IN_DIM) return;
    int b = rowptr[seg], e = rowptr[seg + 1];
    float acc = 0.0f;
    for (int i = b; i < e; ++i) acc += x[elist[i] * IN_DIM + k];
    float inv = (e > b) ? 1.0f / (float)(e - b) : 0.0f;
    mean1[seg * IN_DIM + k] = acc * inv;
}

// h[n,o] = relu(b1[o] + sum_k f[k]*Wcat[k,o]); f = [mean1(60) | x(15)]
__global__ __launch_bounds__(HID) void layer1(
        const float* __restrict__ x, const float* __restrict__ mean1,
        const float* __restrict__ W_rel, const float* __restrict__ W_root,
        const float* __restrict__ b, float* __restrict__ h) {
    int n = blockIdx.x;
    __shared__ float f[N_REL * IN_DIM + IN_DIM];   // 75
    int t = threadIdx.x;
    if (t < N_REL * IN_DIM) f[t] = mean1[n * N_REL * IN_DIM + t];
    else if (t < N_REL * IN_DIM + IN_DIM) f[t] = x[n * IN_DIM + (t - N_REL * IN_DIM)];
    __syncthreads();
    int o = t;
    float acc = b[o];
    #pragma unroll
    for (int k = 0; k < N_REL * IN_DIM; ++k) acc = fmaf(f[k], W_rel[k * HID + o], acc);
    #pragma unroll
    for (int k = 0; k < IN_DIM; ++k) acc = fmaf(f[60 + k], W_root[k * HID + o], acc);
    h[(long)n * HID + o] = fmaxf(acc, 0.0f);
}

// ---------------- layer 2 aggregation: one wave per segment ----------------
__global__ __launch_bounds__(256) void mean2_kernel(const float* __restrict__ h,
                                                    const int* __restrict__ rowptr,
                                                    const int* __restrict__ elist,
                                                    float* __restrict__ mean2) {
    int wid = (int)(((long)blockIdx.x * blockDim.x + threadIdx.x) >> 6);
    if (wid >= NSEG) return;
    int lane = threadIdx.x & 63;
    int b = rowptr[wid], e = rowptr[wid + 1];
    int d0 = lane * 4;                          // [0,256) in steps of 4
    float4 a0 = make_float4(0.f, 0.f, 0.f, 0.f);
    float4 a1 = make_float4(0.f, 0.f, 0.f, 0.f);
    for (int i = b; i < e; ++i) {
        const float* row = h + (long)elist[i] * HID;
        float4 v0 = *(const float4*)(row + d0);
        float4 v1 = *(const float4*)(row + 256 + d0);
        a0.x += v0.x; a0.y += v0.y; a0.z += v0.z; a0.w += v0.w;
        a1.x += v1.x; a1.y += v1.y; a1.z += v1.z; a1.w += v1.w;
    }
    float inv = (e > b) ? 1.0f / (float)(e - b) : 0.0f;
    a0.x *= inv; a0.y *= inv; a0.z *= inv; a0.w *= inv;
    a1.x *= inv; a1.y *= inv; a1.z *= inv; a1.w *= inv;
    float* dst = mean2 + (long)wid * HID;
    *(float4*)(dst + d0) = a0;
    *(float4*)(dst + 256 + d0) = a1;
}

// ---------------- layer 2 GEMM (fused bias+relu+pool) ----------------
// h2[n,o] = relu(b2[o] + sum_{k<2560} A[n,k]*B[k,o]);  out[batch[n]] += h2[n]
//   A[n,k] = k<2048 ? mean2[n*2048+k] : h[n*512+k-2048]
//   B[k,o] = k<2048 ? W2_rel[k*512+o] : W2_root[(k-2048)*512+o]
#define BM 64
#define BN 64
#define BK 16
#define KTOT (N_REL * HID + HID)   // 2560
__global__ __launch_bounds__(256) void layer2_gemm(
        const float* __restrict__ mean2, const float* __restrict__ h,
        const float* __restrict__ W_rel, const float* __restrict__ W_root,
        const float* __restrict__ b, const int* __restrict__ batch,
        float* __restrict__ out) {
    const int bx = blockIdx.x;        // N tile: 0..7
    const int by = blockIdx.y;        // M tile: 0..156
    const int tid = threadIdx.x;
    const int tx = tid & 15, ty = tid >> 4;

    __shared__ float As[BK][BM];
    __shared__ float Bs[BK][BN];

    float acc[4][4] = {};
    const int row0  = by * BM;
    const int col0g = bx * BN;

    const int am  = tid >> 2;           // 0..63
    const int ak0 = (tid & 3) * 4;      // 0,4,8,12
    const int bk  = tid >> 4;           // 0..15
    const int bc0 = (tid & 15) * 4;     // 0..60

    for (int k0 = 0; k0 < KTOT; k0 += BK) {
        int n = row0 + am;
        float4 av = make_float4(0.f, 0.f, 0.f, 0.f);
        int kg = k0 + ak0;
        if (n < N_NODES) {
            if (kg < N_REL * HID) av = *(const float4*)(mean2 + (long)n * (N_REL * HID) + kg);
            else                  av = *(const float4*)(h + (long)n * HID + (kg - N_REL * HID));
        }
        As[ak0 + 0][am] = av.x;
        As[ak0 + 1][am] = av.y;
        As[ak0 + 2][am] = av.z;
        As[ak0 + 3][am] = av.w;
        {
            int kgb = k0 + bk;
            const float* Brow = (kgb < N_REL * HID) ? (W_rel + (long)kgb * HID)
                                                    : (W_root + (long)(kgb - N_REL * HID) * HID);
            *(float4*)&Bs[bk][bc0] = *(const float4*)(Brow + col0g + bc0);
        }
        __syncthreads();
        #pragma unroll
        for (int kk = 0; kk < BK; ++kk) {
            float a[4], bb[4];
            #pragma unroll
            for (int i = 0; i < 4; ++i) a[i] = As[kk][ty * 4 + i];
            #pragma unroll
            for (int j = 0; j < 4; ++j) bb[j] = Bs[kk][tx * 4 + j];
            #pragma unroll
            for (int i = 0; i < 4; ++i)
                #pragma unroll
                for (int j = 0; j < 4; ++j)
                    acc[i][j] = fmaf(a[i], bb[j], acc[i][j]);
        }
        __syncthreads();
    }
    // epilogue: bias + relu + pooled atomic accumulate
    #pragma unroll
    for (int i = 0; i < 4; ++i) {
        int n = row0 + ty * 4 + i;
        if (n >= N_NODES) break;
        int g = batch[n];
        #pragma unroll
        for (int j = 0; j < 4; ++j) {
            int c = col0g + tx * 4 + j;
            float v = fmaxf(acc[i][j] + b[c], 0.0f);
            atomicAdd(&out[(long)g * HID + c], v);
        }
    }
}

// ---------------- pooling finalize ----------------
__global__ void gcnt_kernel(const int* __restrict__ batch, float* __restrict__ gcnt) {
    int n = blockIdx.x * blockDim.x + threadIdx.x;
    if (n >= N_NODES) return;
    atomicAdd(&gcnt[batch[n]], 1.0f);
}

__global__ void pool_div(float* __restrict__ out, const float* __restrict__ gcnt) {
    int tid = blockIdx.x * blockDim.x + threadIdx.x;
    if (tid >= N_GRAPHS * HID) return;
    out[tid] /= fmaxf(gcnt[tid >> 9], 1.0f);
}

// ---------------- launch ----------------
extern "C" void kernel_launch(void* const* d_in, const int* in_sizes, int n_in,
                              void* d_out, int out_size, void* d_ws, size_t ws_size,
                              hipStream_t stream) {
    const float* x       = (const float*)d_in[0];
    const int*   ei      = (const int*)d_in[1];          // [2, E]
    const int*   src     = ei;
    const int*   tgt     = ei + N_EDGES;
    const int*   etype   = (const int*)d_in[2];
    const int*   batch   = (const int*)d_in[3];
    const float* W1_rel  = (const float*)d_in[4];
    const float* W1_root = (const float*)d_in[5];
    const float* b1      = (const float*)d_in[6];
    const float* W2_rel  = (const float*)d_in[7];
    const float* W2_root = (const float*)d_in[8];
    const float* b2      = (const float*)d_in[9];
    float* out = (float*)d_out;

    int*   wsi    = (int*)d_ws;
    float* wsf    = (float*)d_ws;
    int*   hist   = wsi + IOFF_HIST;
    int*   rowptr = wsi + IOFF_ROWPTR;
    int*   cursor = wsi + IOFF_CURSOR;
    int*   elist  = wsi + IOFF_ELIST;
    float* mean1  = wsf + FOFF_MEAN1;
    float* h      = wsf + FOFF_H;
    float* mean2  = wsf + FOFF_MEAN2;
    float* gcnt   = wsf + FOFF_GCNT;

    // zero: hist (160KB), gcnt, out
    hipMemsetAsync(hist, 0, NSEG * sizeof(int), stream);
    hipMemsetAsync(gcnt, 0, N_GRAPHS * sizeof(float), stream);
    hipMemsetAsync(d_out, 0, (size_t)N_GRAPHS * HID * sizeof(float), stream);

    // CSR build
    hist_kernel<<<(N_EDGES + 255) / 256, 256, 0, stream>>>(tgt, etype, hist);
    scan_kernel<<<1, 1024, 0, stream>>>(hist, rowptr, cursor);
    bin_kernel<<<(N_EDGES + 255) / 256, 256, 0, stream>>>(src, tgt, etype, cursor, elist);

    // layer 1
    mean1_kernel<<<(NSEG * 16 + 255) / 256, 256, 0, stream>>>(x, rowptr, elist, mean1);
    layer1<<<N_NODES, HID, 0, stream>>>(x, mean1, W1_rel, W1_root, b1, h);

    // layer 2
    mean2_kernel<<<(NSEG * 64 + 255) / 256, 256, 0, stream>>>(h, rowptr, elist, mean2);
    {
        dim3 grid(HID / BN, (N_NODES + BM - 1) / BM);
        layer2_gemm<<<grid, 256, 0, stream>>>(mean2, h, W2_rel, W2_root, b2, batch, out);
    }

    // pooling finalize
    gcnt_kernel<<<(N_NODES + 255) / 256, 256, 0, stream>>>(batch, gcnt);
    pool_div<<<(N_GRAPHS * HID + 255) / 256, 256, 0, stream>>>(out, gcnt);
}

// Round 3
// 311.193 us; speedup vs baseline: 5.3034x; 2.5230x over previous
//
#include <hip/hip_runtime.h>

#define N_NODES 10000
#define N_EDGES 160000
#define N_REL 4
#define IN_DIM 15
#define HID 512
#define N_GRAPHS 64
#define NSEG (N_NODES * N_REL)     // 40000
#define K2 (N_REL * HID + HID)     // 2560

typedef __attribute__((ext_vector_type(8))) short s16x8;
typedef __attribute__((ext_vector_type(4))) float f32x4;

__device__ __forceinline__ float bf2f(short s) {
    return __uint_as_float(((unsigned)(unsigned short)s) << 16);
}
__device__ __forceinline__ short f2bf(float f) {
    unsigned u = __float_as_uint(f);
    u += 0x7fff + ((u >> 16) & 1);          // RNE
    return (short)(u >> 16);
}

// ---------------- workspace byte offsets ----------------
#define B_HIST   0u           // int  [40000]
#define B_ROWPTR 160000u      // int  [40001]
#define B_CURSOR 320016u      // int  [40000]
#define B_ELIST  480016u      // int  [160000]
#define B_GB     1120016u     // int  [65]
#define B_MEAN1  1120288u     // f32  [NSEG*15]
#define B_H      3520288u     // bf16 [10000*512]
#define B_MEAN2  13760288u    // bf16 [NSEG*512]  (= [n][2048])
#define B_BT     54720288u    // bf16 [512][2560] = W2cat^T
#define B_H2     57341728u    // bf16 [10000*512]
// end = 67,581,728 bytes (< ws_size)

// ---------------- CSR build ----------------
__global__ void hist_kernel(const int* __restrict__ tgt, const int* __restrict__ et,
                            int* __restrict__ hist) {
    int e = blockIdx.x * blockDim.x + threadIdx.x;
    if (e >= N_EDGES) return;
    atomicAdd(&hist[tgt[e] * N_REL + et[e]], 1);
}

__global__ __launch_bounds__(1024) void scan_kernel(const int* __restrict__ hist,
                                                    int* __restrict__ rowptr,
                                                    int* __restrict__ cursor) {
    __shared__ int psums[1024];
    const int t = threadIdx.x;
    const int CH = (NSEG + 1023) / 1024;      // 40
    const int base = t * CH;
    int s = 0;
    for (int i = 0; i < CH; ++i) {
        int idx = base + i;
        if (idx < NSEG) s += hist[idx];
    }
    psums[t] = s;
    __syncthreads();
    for (int off = 1; off < 1024; off <<= 1) {
        int v = 0;
        if (t >= off) v = psums[t - off];
        __syncthreads();
        if (t >= off) psums[t] += v;
        __syncthreads();
    }
    int run = (t == 0) ? 0 : psums[t - 1];
    for (int i = 0; i < CH; ++i) {
        int idx = base + i;
        if (idx < NSEG) {
            rowptr[idx] = run;
            cursor[idx] = run;
            run += hist[idx];
        }
    }
    if (t == 1023) rowptr[NSEG] = psums[1023];
}

__global__ void bin_kernel(const int* __restrict__ src, const int* __restrict__ tgt,
                           const int* __restrict__ et, int* __restrict__ cursor,
                           int* __restrict__ elist) {
    int e = blockIdx.x * blockDim.x + threadIdx.x;
    if (e >= N_EDGES) return;
    int seg = tgt[e] * N_REL + et[e];
    int pos = atomicAdd(&cursor[seg], 1);
    elist[pos] = src[e];
}

// graph boundaries: gb[g] = first node index with batch >= g (batch sorted)
__global__ void gb_kernel(const int* __restrict__ batch, int* __restrict__ gb) {
    int n = blockIdx.x * blockDim.x + threadIdx.x;
    if (n >= N_NODES) return;
    int b = batch[n];
    int bp = (n == 0) ? -1 : batch[n - 1];
    for (int g = bp + 1; g <= b; ++g) gb[g] = n;
    if (n == N_NODES - 1)
        for (int g = b + 1; g <= N_GRAPHS; ++g) gb[g] = N_NODES;
}

// ---------------- layer 1 ----------------
__global__ void mean1_kernel(const float* __restrict__ x, const int* __restrict__ rowptr,
                             const int* __restrict__ elist, float* __restrict__ mean1) {
    int tid = blockIdx.x * blockDim.x + threadIdx.x;
    if (tid >= NSEG * 16) return;
    int seg = tid >> 4, k = tid & 15;
    if (k >= IN_DIM) return;
    int b = rowptr[seg], e = rowptr[seg + 1];
    float acc = 0.0f;
    for (int i = b; i < e; ++i) acc += x[elist[i] * IN_DIM + k];
    float inv = (e > b) ? 1.0f / (float)(e - b) : 0.0f;
    mean1[seg * IN_DIM + k] = acc * inv;
}

// 8 nodes per block: W1 read once per 8 nodes; h output bf16
__global__ __launch_bounds__(512) void layer1_kernel(
        const float* __restrict__ x, const float* __restrict__ mean1,
        const float* __restrict__ W1_rel, const float* __restrict__ W1_root,
        const float* __restrict__ b1, short* __restrict__ h) {
    const int nb = blockIdx.x * 8;
    __shared__ float f[8][75];
    const int t = threadIdx.x;
    for (int idx = t; idx < 600; idx += 512) {
        int m = idx / 75, k = idx - m * 75;
        int n = nb + m;
        f[m][k] = (k < 60) ? mean1[n * 60 + k] : x[n * IN_DIM + (k - 60)];
    }
    __syncthreads();
    const int o = t;
    float acc[8];
    float bias = b1[o];
    #pragma unroll
    for (int m = 0; m < 8; ++m) acc[m] = bias;
    for (int k = 0; k < 60; ++k) {
        float w = W1_rel[k * HID + o];
        #pragma unroll
        for (int m = 0; m < 8; ++m) acc[m] = fmaf(f[m][k], w, acc[m]);
    }
    for (int k = 0; k < 15; ++k) {
        float w = W1_root[k * HID + o];
        #pragma unroll
        for (int m = 0; m < 8; ++m) acc[m] = fmaf(f[m][60 + k], w, acc[m]);
    }
    #pragma unroll
    for (int m = 0; m < 8; ++m)
        h[(long)(nb + m) * HID + o] = f2bf(fmaxf(acc[m], 0.0f));
}

// ---------------- layer 2 aggregation: one wave per segment, bf16 in/out ----------------
__global__ __launch_bounds__(256) void mean2_kernel(
        const short* __restrict__ h, const int* __restrict__ rowptr,
        const int* __restrict__ elist, short* __restrict__ mean2) {
    const int wid = (int)((blockIdx.x * 256u + threadIdx.x) >> 6);
    if (wid >= NSEG) return;
    const int lane = threadIdx.x & 63;
    const int b = rowptr[wid], e = rowptr[wid + 1];
    float acc[8] = {0.f,0.f,0.f,0.f,0.f,0.f,0.f,0.f};
    for (int i = b; i < e; ++i) {
        const s16x8 v = *(const s16x8*)(h + (long)elist[i] * HID + lane * 8);
        #pragma unroll
        for (int j = 0; j < 8; ++j) acc[j] += bf2f(v[j]);
    }
    const float inv = (e > b) ? 1.0f / (float)(e - b) : 0.0f;
    s16x8 o;
    #pragma unroll
    for (int j = 0; j < 8; ++j) o[j] = f2bf(acc[j] * inv);
    *(s16x8*)(mean2 + (long)wid * HID + lane * 8) = o;
}

// ---------------- W2cat transpose -> Bt[o][k] bf16 ----------------
__global__ __launch_bounds__(256) void wtrans_kernel(
        const float* __restrict__ W2_rel, const float* __restrict__ W2_root,
        short* __restrict__ Bt) {
    __shared__ float tile[64][65];
    const int k0 = blockIdx.x * 64;   // 40
    const int o0 = blockIdx.y * 64;   // 8
    const int t = threadIdx.x;
    #pragma unroll
    for (int i = 0; i < 16; ++i) {
        int idx = t + i * 256;
        int kk = idx >> 6, oo = idx & 63;
        int k = k0 + kk;
        float v = (k < N_REL * HID) ? W2_rel[(long)k * HID + o0 + oo]
                                    : W2_root[(long)(k - N_REL * HID) * HID + o0 + oo];
        tile[kk][oo] = v;
    }
    __syncthreads();
    #pragma unroll
    for (int i = 0; i < 16; ++i) {
        int idx = t + i * 256;
        int oo = idx >> 6, kk = idx & 63;
        Bt[(long)(o0 + oo) * K2 + k0 + kk] = f2bf(tile[kk][oo]);
    }
}

// ---------------- layer 2 GEMM: [10000,2560]x[2560,512] bf16 MFMA ----------------
// A[n][k] = k<2048 ? mean2[n*2048+k] : h[n*512+k-2048]; B via Bt[o][k].
// Tile 64(M)x128(N), BK=64. 4 waves, wave w covers cols w*32..w*32+31 (acc 4x2 frags).
// LDS tiles [row][64k] bf16, 128B rows, XOR-swizzle slot^=(row&7) (G4);
// staged linear via global_load_lds with pre-swizzled global source (rule #21).
#define GM 64
#define GN 128
#define GK 64
__global__ __launch_bounds__(256) void gemm2_kernel(
        const short* __restrict__ mean2, const short* __restrict__ h,
        const short* __restrict__ Bt, const float* __restrict__ b2,
        short* __restrict__ h2) {
    __shared__ __align__(16) short Al[GM * GK];   // 8 KB
    __shared__ __align__(16) short Bl[GN * GK];   // 16 KB
    const int tid = threadIdx.x;
    const int lane = tid & 63;
    const int w = tid >> 6;
    const int m0 = blockIdx.y * GM;
    const int n0 = blockIdx.x * GN;
    const int l15 = lane & 15, lg = lane >> 4;

    f32x4 acc[4][2];
    #pragma unroll
    for (int a = 0; a < 4; ++a)
        #pragma unroll
        for (int bb = 0; bb < 2; ++bb)
            acc[a][bb] = (f32x4){0.f, 0.f, 0.f, 0.f};

    for (int k0 = 0; k0 < K2; k0 += GK) {
        __syncthreads();                       // previous iter's LDS reads done
        // stage A: 64 rows x 8 chunks = 512
        #pragma unroll
        for (int i = 0; i < 2; ++i) {
            int c = tid + i * 256;
            int row = c >> 3, slot = c & 7;
            int srcslot = slot ^ (row & 7);
            int n = m0 + row; if (n > N_NODES - 1) n = N_NODES - 1;
            int kg = k0 + srcslot * 8;
            const short* gsrc = (kg < N_REL * HID)
                ? (mean2 + (long)n * (N_REL * HID) + kg)
                : (h + (long)n * HID + (kg - N_REL * HID));
            __builtin_amdgcn_global_load_lds(
                (const __attribute__((address_space(1))) void*)gsrc,
                (__attribute__((address_space(3))) void*)(Al + c * 8), 16, 0, 0);
        }
        // stage B: 128 rows x 8 chunks = 1024
        #pragma unroll
        for (int i = 0; i < 4; ++i) {
            int c = tid + i * 256;
            int row = c >> 3, slot = c & 7;
            int srcslot = slot ^ (row & 7);
            const short* gsrc = Bt + (long)(n0 + row) * K2 + k0 + srcslot * 8;
            __builtin_amdgcn_global_load_lds(
                (const __attribute__((address_space(1))) void*)gsrc,
                (__attribute__((address_space(3))) void*)(Bl + c * 8), 16, 0, 0);
        }
        asm volatile("s_waitcnt vmcnt(0)" ::: "memory");
        __syncthreads();
        // compute: 2 k-halves x (4m x 2n) MFMA
        #pragma unroll
        for (int hh = 0; hh < 2; ++hh) {
            s16x8 af[4], bfr[2];
            #pragma unroll
            for (int fm = 0; fm < 4; ++fm) {
                int row = fm * 16 + l15;
                int slot = (hh * 4 + lg) ^ (row & 7);
                af[fm] = *(const s16x8*)(Al + row * GK + slot * 8);
            }
            #pragma unroll
            for (int fn = 0; fn < 2; ++fn) {
                int row = w * 32 + fn * 16 + l15;
                int slot = (hh * 4 + lg) ^ (row & 7);
                bfr[fn] = *(const s16x8*)(Bl + row * GK + slot * 8);
            }
            #pragma unroll
            for (int fm = 0; fm < 4; ++fm)
                #pragma unroll
                for (int fn = 0; fn < 2; ++fn)
                    asm("v_mfma_f32_16x16x32_bf16 %0, %1, %2, %0"
                        : "+v"(acc[fm][fn]) : "v"(af[fm]), "v"(bfr[fn]));
        }
    }
    // epilogue: bias + relu -> h2 bf16
    #pragma unroll
    for (int fm = 0; fm < 4; ++fm) {
        int rbase = m0 + fm * 16 + 4 * lg;
        #pragma unroll
        for (int fn = 0; fn < 2; ++fn) {
            int col = n0 + w * 32 + fn * 16 + l15;
            float bias = b2[col];
            #pragma unroll
            for (int r = 0; r < 4; ++r) {
                int n = rbase + r;
                if (n < N_NODES)
                    h2[(long)n * HID + col] = f2bf(fmaxf(acc[fm][fn][r] + bias, 0.f));
            }
        }
    }
}

// ---------------- pool: no atomics (batch sorted -> contiguous ranges) ----------------
__global__ __launch_bounds__(256) void pool_kernel(const short* __restrict__ h2,
                                                   const int* __restrict__ gb,
                                                   float* __restrict__ out) {
    const int g = blockIdx.x;
    const int t = threadIdx.x;
    const int s = gb[g], e = gb[g + 1];
    float a0 = 0.f, a1 = 0.f;
    const int* base = (const int*)h2;
    for (int n = s; n < e; ++n) {
        int v = base[n * (HID / 2) + t];
        a0 += bf2f((short)(v & 0xffff));
        a1 += bf2f((short)((unsigned)v >> 16));
    }
    const float inv = (e > s) ? 1.0f / (float)(e - s) : 0.f;
    out[g * HID + t * 2]     = a0 * inv;
    out[g * HID + t * 2 + 1] = a1 * inv;
}

// ---------------- launch ----------------
extern "C" void kernel_launch(void* const* d_in, const int* in_sizes, int n_in,
                              void* d_out, int out_size, void* d_ws, size_t ws_size,
                              hipStream_t stream) {
    const float* x       = (const float*)d_in[0];
    const int*   ei      = (const int*)d_in[1];
    const int*   src     = ei;
    const int*   tgt     = ei + N_EDGES;
    const int*   etype   = (const int*)d_in[2];
    const int*   batch   = (const int*)d_in[3];
    const float* W1_rel  = (const float*)d_in[4];
    const float* W1_root = (const float*)d_in[5];
    const float* b1      = (const float*)d_in[6];
    const float* W2_rel  = (const float*)d_in[7];
    const float* W2_root = (const float*)d_in[8];
    const float* b2      = (const float*)d_in[9];
    float* out = (float*)d_out;

    char* ws = (char*)d_ws;
    int*   hist   = (int*)(ws + B_HIST);
    int*   rowptr = (int*)(ws + B_ROWPTR);
    int*   cursor = (int*)(ws + B_CURSOR);
    int*   elist  = (int*)(ws + B_ELIST);
    int*   gb     = (int*)(ws + B_GB);
    float* mean1  = (float*)(ws + B_MEAN1);
    short* h      = (short*)(ws + B_H);
    short* mean2  = (short*)(ws + B_MEAN2);
    short* Bt     = (short*)(ws + B_BT);
    short* h2     = (short*)(ws + B_H2);

    hipMemsetAsync(hist, 0, NSEG * sizeof(int), stream);

    hist_kernel<<<(N_EDGES + 255) / 256, 256, 0, stream>>>(tgt, etype, hist);
    scan_kernel<<<1, 1024, 0, stream>>>(hist, rowptr, cursor);
    bin_kernel<<<(N_EDGES + 255) / 256, 256, 0, stream>>>(src, tgt, etype, cursor, elist);
    gb_kernel<<<(N_NODES + 255) / 256, 256, 0, stream>>>(batch, gb);

    mean1_kernel<<<(NSEG * 16 + 255) / 256, 256, 0, stream>>>(x, rowptr, elist, mean1);
    layer1_kernel<<<N_NODES / 8, 512, 0, stream>>>(x, mean1, W1_rel, W1_root, b1, h);

    mean2_kernel<<<NSEG / 4, 256, 0, stream>>>(h, rowptr, elist, mean2);
    wtrans_kernel<<<dim3(K2 / 64, HID / 64), 256, 0, stream>>>(W2_rel, W2_root, Bt);

    gemm2_kernel<<<dim3(HID / GN, (N_NODES + GM - 1) / GM), 256, 0, stream>>>(
        mean2, h, Bt, b2, h2);

    pool_kernel<<<N_GRAPHS, 256, 0, stream>>>(h2, gb, out);
}

// Round 4
// 225.493 us; speedup vs baseline: 7.3190x; 1.3801x over previous
//
#include <hip/hip_runtime.h>

#define N_NODES 10000
#define N_EDGES 160000
#define N_REL 4
#define IN_DIM 15
#define HID 512
#define N_GRAPHS 64
#define NSEG (N_NODES * N_REL)     // 40000
#define K2 (N_REL * HID + HID)     // 2560

typedef __attribute__((ext_vector_type(8))) short s16x8;
typedef __attribute__((ext_vector_type(4))) float f32x4;

__device__ __forceinline__ float bf2f(short s) {
    return __uint_as_float(((unsigned)(unsigned short)s) << 16);
}
__device__ __forceinline__ short f2bf(float f) {
    unsigned u = __float_as_uint(f);
    u += 0x7fff + ((u >> 16) & 1);          // RNE
    return (short)(u >> 16);
}

// ---------------- workspace byte offsets ----------------
#define B_HIST   0u           // int  [40000]
#define B_TOTAL  160000u      // int  [1]        (memset covers hist+total)
#define B_BEG    160004u      // int  [40000]
#define B_CURSOR 320004u      // int  [40000]
#define B_ELIST  480004u      // int  [160000]
#define B_GB     1120004u     // int  [65]
#define B_MEAN1  1120272u     // f32  [NSEG*15]
#define B_H      3520272u     // bf16 [10000*512]
#define B_MEAN2  13760272u    // bf16 [NSEG*512]
#define B_BT     54720272u    // bf16 [512][2560] = W2cat^T
#define B_H2     57341712u    // bf16 [10000*512]
// end = 67,581,712 bytes

// ---------------- CSR build ----------------
__global__ void hist_kernel(const int* __restrict__ tgt, const int* __restrict__ et,
                            int* __restrict__ hist) {
    int e = blockIdx.x * blockDim.x + threadIdx.x;
    if (e >= N_EDGES) return;
    atomicAdd(&hist[tgt[e] * N_REL + et[e]], 1);
}

// parallel range allocator: beg[seg] disjoint ranges (order-free, no global scan)
__global__ __launch_bounds__(256) void alloc_kernel(const int* __restrict__ hist,
                                                    int* __restrict__ beg,
                                                    int* __restrict__ cursor,
                                                    int* __restrict__ total) {
    int i = blockIdx.x * blockDim.x + threadIdx.x;
    int c = (i < NSEG) ? hist[i] : 0;
    int lane = threadIdx.x & 63;
    int incl = c;
    #pragma unroll
    for (int off = 1; off < 64; off <<= 1) {
        int v = __shfl_up(incl, off, 64);
        if (lane >= off) incl += v;
    }
    int wtot = __shfl(incl, 63, 64);
    int base = 0;
    if (lane == 63) base = atomicAdd(total, wtot);
    base = __shfl(base, 63, 64);
    if (i < NSEG) {
        int b = base + incl - c;
        beg[i] = b;
        cursor[i] = b;
    }
}

__global__ void bin_kernel(const int* __restrict__ src, const int* __restrict__ tgt,
                           const int* __restrict__ et, int* __restrict__ cursor,
                           int* __restrict__ elist) {
    int e = blockIdx.x * blockDim.x + threadIdx.x;
    if (e >= N_EDGES) return;
    int seg = tgt[e] * N_REL + et[e];
    int pos = atomicAdd(&cursor[seg], 1);
    elist[pos] = src[e];
}

// graph boundaries: gb[g] = first node index with batch >= g (batch sorted)
__global__ void gb_kernel(const int* __restrict__ batch, int* __restrict__ gb) {
    int n = blockIdx.x * blockDim.x + threadIdx.x;
    if (n >= N_NODES) return;
    int b = batch[n];
    int bp = (n == 0) ? -1 : batch[n - 1];
    for (int g = bp + 1; g <= b; ++g) gb[g] = n;
    if (n == N_NODES - 1)
        for (int g = b + 1; g <= N_GRAPHS; ++g) gb[g] = N_NODES;
}

// ---------------- layer 1 ----------------
__global__ void mean1_kernel(const float* __restrict__ x, const int* __restrict__ beg,
                             const int* __restrict__ hist, const int* __restrict__ elist,
                             float* __restrict__ mean1) {
    int tid = blockIdx.x * blockDim.x + threadIdx.x;
    if (tid >= NSEG * 16) return;
    int seg = tid >> 4, k = tid & 15;
    if (k >= IN_DIM) return;
    int b = beg[seg], cnt = hist[seg], e = b + cnt;
    float acc = 0.0f;
    for (int i = b; i < e; ++i) acc += x[elist[i] * IN_DIM + k];
    float inv = (cnt > 0) ? 1.0f / (float)cnt : 0.0f;
    mean1[seg * IN_DIM + k] = acc * inv;
}

// 8 nodes per block: W1 read once per 8 nodes; h output bf16
__global__ __launch_bounds__(512) void layer1_kernel(
        const float* __restrict__ x, const float* __restrict__ mean1,
        const float* __restrict__ W1_rel, const float* __restrict__ W1_root,
        const float* __restrict__ b1, short* __restrict__ h) {
    const int nb = blockIdx.x * 8;
    __shared__ float f[8][75];
    const int t = threadIdx.x;
    for (int idx = t; idx < 600; idx += 512) {
        int m = idx / 75, k = idx - m * 75;
        int n = nb + m;
        f[m][k] = (k < 60) ? mean1[n * 60 + k] : x[n * IN_DIM + (k - 60)];
    }
    __syncthreads();
    const int o = t;
    float acc[8];
    float bias = b1[o];
    #pragma unroll
    for (int m = 0; m < 8; ++m) acc[m] = bias;
    for (int k = 0; k < 60; ++k) {
        float w = W1_rel[k * HID + o];
        #pragma unroll
        for (int m = 0; m < 8; ++m) acc[m] = fmaf(f[m][k], w, acc[m]);
    }
    for (int k = 0; k < 15; ++k) {
        float w = W1_root[k * HID + o];
        #pragma unroll
        for (int m = 0; m < 8; ++m) acc[m] = fmaf(f[m][60 + k], w, acc[m]);
    }
    #pragma unroll
    for (int m = 0; m < 8; ++m)
        h[(long)(nb + m) * HID + o] = f2bf(fmaxf(acc[m], 0.0f));
}

// ---------------- layer 2 aggregation: one wave per segment, bf16 in/out ----------------
__global__ __launch_bounds__(256) void mean2_kernel(
        const short* __restrict__ h, const int* __restrict__ beg,
        const int* __restrict__ hist, const int* __restrict__ elist,
        short* __restrict__ mean2) {
    const int wid = (int)((blockIdx.x * 256u + threadIdx.x) >> 6);
    if (wid >= NSEG) return;
    const int lane = threadIdx.x & 63;
    const int b = beg[wid], cnt = hist[wid], e = b + cnt;
    float acc[8] = {0.f,0.f,0.f,0.f,0.f,0.f,0.f,0.f};
    for (int i = b; i < e; ++i) {
        const s16x8 v = *(const s16x8*)(h + (long)elist[i] * HID + lane * 8);
        #pragma unroll
        for (int j = 0; j < 8; ++j) acc[j] += bf2f(v[j]);
    }
    const float inv = (cnt > 0) ? 1.0f / (float)cnt : 0.0f;
    s16x8 o;
    #pragma unroll
    for (int j = 0; j < 8; ++j) o[j] = f2bf(acc[j] * inv);
    *(s16x8*)(mean2 + (long)wid * HID + lane * 8) = o;
}

// ---------------- W2cat transpose -> Bt[o][k] bf16 ----------------
__global__ __launch_bounds__(256) void wtrans_kernel(
        const float* __restrict__ W2_rel, const float* __restrict__ W2_root,
        short* __restrict__ Bt) {
    __shared__ float tile[64][65];
    const int k0 = blockIdx.x * 64;   // 40
    const int o0 = blockIdx.y * 64;   // 8
    const int t = threadIdx.x;
    #pragma unroll
    for (int i = 0; i < 16; ++i) {
        int idx = t + i * 256;
        int kk = idx >> 6, oo = idx & 63;
        int k = k0 + kk;
        float v = (k < N_REL * HID) ? W2_rel[(long)k * HID + o0 + oo]
                                    : W2_root[(long)(k - N_REL * HID) * HID + o0 + oo];
        tile[kk][oo] = v;
    }
    __syncthreads();
    #pragma unroll
    for (int i = 0; i < 16; ++i) {
        int idx = t + i * 256;
        int oo = idx >> 6, kk = idx & 63;
        Bt[(long)(o0 + oo) * K2 + k0 + kk] = f2bf(tile[kk][oo]);
    }
}

// ---------------- layer 2 GEMM: [10000,2560]x[2560,512] bf16 MFMA ----------------
// Double-buffered LDS, stage(t+1) issued before compute(t), one raw barrier/tile.
#define GM 64
#define GN 128
#define GK 64
#define NT (K2 / GK)   // 40
__global__ __launch_bounds__(256) void gemm2_kernel(
        const short* __restrict__ mean2, const short* __restrict__ h,
        const short* __restrict__ Bt, const float* __restrict__ b2,
        short* __restrict__ h2) {
    __shared__ __align__(16) short Al[2][GM * GK];   // 2 x 8 KB
    __shared__ __align__(16) short Bl[2][GN * GK];   // 2 x 16 KB
    const int tid = threadIdx.x;
    const int lane = tid & 63;
    const int w = tid >> 6;
    const int m0 = blockIdx.y * GM;
    const int n0 = blockIdx.x * GN;
    const int l15 = lane & 15, lg = lane >> 4;

    f32x4 acc[4][2];
    #pragma unroll
    for (int a = 0; a < 4; ++a)
        #pragma unroll
        for (int bb = 0; bb < 2; ++bb)
            acc[a][bb] = (f32x4){0.f, 0.f, 0.f, 0.f};

    // stage helper expanded inline: 2 A-chunks + 4 B-chunks per thread
#define STAGE(buf, k0)                                                           \
    {                                                                            \
        _Pragma("unroll")                                                        \
        for (int i = 0; i < 2; ++i) {                                            \
            int c = tid + i * 256;                                               \
            int row = c >> 3, slot = c & 7;                                      \
            int srcslot = slot ^ (row & 7);                                      \
            int n = m0 + row; if (n > N_NODES - 1) n = N_NODES - 1;              \
            int kg = (k0) + srcslot * 8;                                         \
            const short* gsrc = (kg < N_REL * HID)                               \
                ? (mean2 + (long)n * (N_REL * HID) + kg)                         \
                : (h + (long)n * HID + (kg - N_REL * HID));                      \
            __builtin_amdgcn_global_load_lds(                                    \
                (const __attribute__((address_space(1))) void*)gsrc,             \
                (__attribute__((address_space(3))) void*)(Al[buf] + c * 8),      \
                16, 0, 0);                                                       \
        }                                                                        \
        _Pragma("unroll")                                                        \
        for (int i = 0; i < 4; ++i) {                                            \
            int c = tid + i * 256;                                               \
            int row = c >> 3, slot = c & 7;                                      \
            int srcslot = slot ^ (row & 7);                                      \
            const short* gsrc = Bt + (long)(n0 + row) * K2 + (k0) + srcslot * 8; \
            __builtin_amdgcn_global_load_lds(                                    \
                (const __attribute__((address_space(1))) void*)gsrc,             \
                (__attribute__((address_space(3))) void*)(Bl[buf] + c * 8),      \
                16, 0, 0);                                                       \
        }                                                                        \
    }

    // prologue
    STAGE(0, 0);
    asm volatile("s_waitcnt vmcnt(0)" ::: "memory");
    __builtin_amdgcn_s_barrier();
    asm volatile("" ::: "memory");

    int cur = 0;
    for (int t = 0; t < NT; ++t) {
        if (t + 1 < NT) STAGE(cur ^ 1, (t + 1) * GK);
        // compute from buf[cur]
        #pragma unroll
        for (int hh = 0; hh < 2; ++hh) {
            s16x8 af[4], bfr[2];
            #pragma unroll
            for (int fm = 0; fm < 4; ++fm) {
                int row = fm * 16 + l15;
                int slot = (hh * 4 + lg) ^ (row & 7);
                af[fm] = *(const s16x8*)(Al[cur] + row * GK + slot * 8);
            }
            #pragma unroll
            for (int fn = 0; fn < 2; ++fn) {
                int row = w * 32 + fn * 16 + l15;
                int slot = (hh * 4 + lg) ^ (row & 7);
                bfr[fn] = *(const s16x8*)(Bl[cur] + row * GK + slot * 8);
            }
            #pragma unroll
            for (int fm = 0; fm < 4; ++fm)
                #pragma unroll
                for (int fn = 0; fn < 2; ++fn)
                    asm("v_mfma_f32_16x16x32_bf16 %0, %1, %2, %0"
                        : "+v"(acc[fm][fn]) : "v"(af[fm]), "v"(bfr[fn]));
        }
        asm volatile("s_waitcnt vmcnt(0)" ::: "memory");
        __builtin_amdgcn_s_barrier();
        asm volatile("" ::: "memory");
        cur ^= 1;
    }
#undef STAGE

    // epilogue: bias + relu -> h2 bf16
    #pragma unroll
    for (int fm = 0; fm < 4; ++fm) {
        int rbase = m0 + fm * 16 + 4 * lg;
        #pragma unroll
        for (int fn = 0; fn < 2; ++fn) {
            int col = n0 + w * 32 + fn * 16 + l15;
            float bias = b2[col];
            #pragma unroll
            for (int r = 0; r < 4; ++r) {
                int n = rbase + r;
                if (n < N_NODES)
                    h2[(long)n * HID + col] = f2bf(fmaxf(acc[fm][fn][r] + bias, 0.f));
            }
        }
    }
}

// ---------------- pool: no atomics (batch sorted -> contiguous ranges) ----------------
__global__ __launch_bounds__(256) void pool_kernel(const short* __restrict__ h2,
                                                   const int* __restrict__ gb,
                                                   float* __restrict__ out) {
    const int g = blockIdx.x;
    const int t = threadIdx.x;
    const int s = gb[g], e = gb[g + 1];
    float a0 = 0.f, a1 = 0.f;
    const int* base = (const int*)h2;
    for (int n = s; n < e; ++n) {
        int v = base[n * (HID / 2) + t];
        a0 += bf2f((short)(v & 0xffff));
        a1 += bf2f((short)((unsigned)v >> 16));
    }
    const float inv = (e > s) ? 1.0f / (float)(e - s) : 0.f;
    out[g * HID + t * 2]     = a0 * inv;
    out[g * HID + t * 2 + 1] = a1 * inv;
}

// ---------------- launch ----------------
extern "C" void kernel_launch(void* const* d_in, const int* in_sizes, int n_in,
                              void* d_out, int out_size, void* d_ws, size_t ws_size,
                              hipStream_t stream) {
    const float* x       = (const float*)d_in[0];
    const int*   ei      = (const int*)d_in[1];
    const int*   src     = ei;
    const int*   tgt     = ei + N_EDGES;
    const int*   etype   = (const int*)d_in[2];
    const int*   batch   = (const int*)d_in[3];
    const float* W1_rel  = (const float*)d_in[4];
    const float* W1_root = (const float*)d_in[5];
    const float* b1      = (const float*)d_in[6];
    const float* W2_rel  = (const float*)d_in[7];
    const float* W2_root = (const float*)d_in[8];
    const float* b2      = (const float*)d_in[9];
    float* out = (float*)d_out;

    char* ws = (char*)d_ws;
    int*   hist   = (int*)(ws + B_HIST);
    int*   total  = (int*)(ws + B_TOTAL);
    int*   beg    = (int*)(ws + B_BEG);
    int*   cursor = (int*)(ws + B_CURSOR);
    int*   elist  = (int*)(ws + B_ELIST);
    int*   gb     = (int*)(ws + B_GB);
    float* mean1  = (float*)(ws + B_MEAN1);
    short* h      = (short*)(ws + B_H);
    short* mean2  = (short*)(ws + B_MEAN2);
    short* Bt     = (short*)(ws + B_BT);
    short* h2     = (short*)(ws + B_H2);

    hipMemsetAsync(hist, 0, NSEG * sizeof(int) + sizeof(int), stream);  // hist + total

    hist_kernel<<<(N_EDGES + 255) / 256, 256, 0, stream>>>(tgt, etype, hist);
    alloc_kernel<<<(NSEG + 255) / 256, 256, 0, stream>>>(hist, beg, cursor, total);
    bin_kernel<<<(N_EDGES + 255) / 256, 256, 0, stream>>>(src, tgt, etype, cursor, elist);
    gb_kernel<<<(N_NODES + 255) / 256, 256, 0, stream>>>(batch, gb);

    mean1_kernel<<<(NSEG * 16 + 255) / 256, 256, 0, stream>>>(x, beg, hist, elist, mean1);
    layer1_kernel<<<N_NODES / 8, 512, 0, stream>>>(x, mean1, W1_rel, W1_root, b1, h);

    mean2_kernel<<<NSEG / 4, 256, 0, stream>>>(h, beg, hist, elist, mean2);
    wtrans_kernel<<<dim3(K2 / 64, HID / 64), 256, 0, stream>>>(W2_rel, W2_root, Bt);

    gemm2_kernel<<<dim3(HID / GN, (N_NODES + GM - 1) / GM), 256, 0, stream>>>(
        mean2, h, Bt, b2, h2);

    pool_kernel<<<N_GRAPHS, 256, 0, stream>>>(h2, gb, out);
}